// Round 16
// baseline (431.443 us; speedup 1.0000x reference)
//
#include <hip/hip_runtime.h>
#include <hip/hip_cooperative_groups.h>
#include <math.h>

namespace cg = cooperative_groups;

// (B,N,K,D,V,L) = (16,512,16,256,64,2)
#define Kn 16
#define Dd 256
#define NC 1024
#define MR 8192

typedef _Float16 h8 __attribute__((ext_vector_type(8)));
typedef _Float16 h4 __attribute__((ext_vector_type(4)));
typedef _Float16 h2 __attribute__((ext_vector_type(2)));
typedef float f4 __attribute__((ext_vector_type(4)));

__device__ __forceinline__ void gload16(_Float16* lds, const _Float16* g) {
  __builtin_amdgcn_global_load_lds(
      (const __attribute__((address_space(1))) void*)g,
      (__attribute__((address_space(3))) void*)lds, 16, 0, 0);
}

__device__ __forceinline__ float fsigm(float x) { return 1.f / (1.f + __expf(-x)); }
__device__ __forceinline__ float ftanh(float x) { return 2.f / (1.f + __expf(-2.f * x)) - 1.f; }

// ---------------------------------------------------------------------------
// Shared device bodies (used by both cooperative and fallback paths)
// Fragment: Wf[kt][nt][lane][j], k = kt*32+(lane>>4)*8+j, cp = nt*16+(lane&15)
// col perm: cp = 64*(d>>4)+16*g+(d&15)  <->  c = g*256+d
// ---------------------------------------------------------------------------

// P role: 4 vv per block pb (0..127), quarter cq of columns.
__device__ __forceinline__ void role_P(int pb, int t, char* smem,
    const float* __restrict__ emb,
    const float* __restrict__ Wi, const float* __restrict__ Wo,
    const float* __restrict__ Ui, const float* __restrict__ Uo,
    _Float16* __restrict__ W0f) {
  float* seT = (float*)smem;             // [256 dd][4 r] f32 (4 KB)
  float* sa = (float*)(smem + 4096);     // [4 ds][4 r][64 l] f4 (16 KB)
  const int vgrp = pb >> 2, cq = pb & 3;
  const int dir = vgrp >> 4;
  const int v0 = (vgrp & 15) * 4;
  const float* Wa = dir ? Wo : Wi;
  const float* Ua = dir ? Uo : Ui;
#pragma unroll
  for (int r = 0; r < 4; r++) seT[t * 4 + r] = emb[(v0 + r) * 256 + t];
  __syncthreads();

  const int l = t & 63, ds = t >> 6;
  const int cp0 = cq * 256 + l * 4;
  const int g = (cp0 >> 4) & 3;
  const int d0 = ((cp0 >> 6) << 4) + (cp0 & 15);
  const int c0 = g * 256 + d0;
  const float* wp = Wa + (size_t)(256 + ds * 64) * NC + c0;
  const float* up = Ua + (size_t)(256 + ds * 64) * NC + c0;
  const float* sT = seT + (ds * 64) * 4;

  f4 av[4] = {};
  for (int bb8 = 0; bb8 < 8; bb8++) {
    f4 wv8[8], uv8[8];
#pragma unroll
    for (int ii = 0; ii < 8; ii++) {  // 16 loads in flight
      const int dd = bb8 * 8 + ii;
      wv8[ii] = *(const f4*)(wp + (size_t)dd * NC);
      uv8[ii] = *(const f4*)(up + (size_t)dd * NC);
    }
    __builtin_amdgcn_sched_barrier(0);
#pragma unroll
    for (int ii = 0; ii < 8; ii++) {
      const int dd = bb8 * 8 + ii;
      const f4 wv = wv8[ii] + uv8[ii];
      const f4 s0 = *(const f4*)&sT[dd * 4];
      av[0] += s0[0] * wv;
      av[1] += s0[1] * wv;
      av[2] += s0[2] * wv;
      av[3] += s0[3] * wv;
    }
  }
#pragma unroll
  for (int r = 0; r < 4; r++) *(f4*)&sa[((ds * 4 + r) * 64 + l) * 4] = av[r];
  __syncthreads();
  {
    const int r = t >> 6, fl = t & 63;
    f4 s = {0.f, 0.f, 0.f, 0.f};
#pragma unroll
    for (int d = 0; d < 4; d++) s += *(const f4*)&sa[((d * 4 + r) * 64 + fl) * 4];
    const int vvg = vgrp * 4 + r;
    const int kt = 16 + (vvg >> 5);
    const int lhi = (vvg >> 3) & 3;
    const int j = vvg & 7;
    const int cpb = cq * 256 + fl * 4;
#pragma unroll
    for (int i = 0; i < 4; i++) {
      const int cp = cpb + i;
      W0f[kt * 32768 + (cp >> 4) * 512 + (lhi * 16 + (cp & 15)) * 8 + j] = (_Float16)s[i];
    }
  }
}

// fold role: plane p (0..31). W0' = W_top + U_top ; Wl = U_top.
__device__ __forceinline__ void role_fold(int p, int t,
    const float* __restrict__ Wi, const float* __restrict__ Wo,
    const float* __restrict__ Ui, const float* __restrict__ Uo,
    _Float16* __restrict__ W0f, _Float16* __restrict__ Wlf) {
  const int kk = t >> 3;
  const int tc = t & 7;
  const int k = (p & 15) * 32 + kk;
  const float* rowp;
  const float* rowp2 = nullptr;
  if (p < 16) {
    rowp  = (k < 256) ? Wi + (size_t)k * NC : Wo + (size_t)(k - 256) * NC;
    rowp2 = (k < 256) ? Ui + (size_t)k * NC : Uo + (size_t)(k - 256) * NC;
  } else {
    rowp  = (k < 256) ? Ui + (size_t)k * NC : Uo + (size_t)(k - 256) * NC;
  }
  _Float16* dst = (p < 16) ? (W0f + p * 32768) : (Wlf + (p - 16) * 32768);
  const int lane0 = (kk >> 3) * 16;
  const int j = kk & 7;
  for (int bb8 = 0; bb8 < 4; bb8++) {
    f4 w8[8], u8[8];
#pragma unroll
    for (int ii = 0; ii < 8; ii++) {
      const int c = (bb8 * 8 + ii) * 32 + tc * 4;
      w8[ii] = *(const f4*)(rowp + c);
      if (p < 16) u8[ii] = *(const f4*)(rowp2 + c);
    }
    __builtin_amdgcn_sched_barrier(0);
#pragma unroll
    for (int ii = 0; ii < 8; ii++) {
      const int c = (bb8 * 8 + ii) * 32 + tc * 4;
      const int g = c >> 8, d = c & 255;
      const int nt = 4 * (d >> 4) + g;
      const int lb = lane0 + (d & 15);
      f4 v = w8[ii];
      if (p < 16) v += u8[ii];
#pragma unroll
      for (int q = 0; q < 4; q++)
        dst[nt * 512 + (lb + q) * 8 + j] = (_Float16)v[q];
    }
  }
}

// agg0 single row: f32 gathers + inline bins -> X.
__device__ __forceinline__ void agg0_row(int row, int lane,
    const float* __restrict__ node_reps,
    const int* __restrict__ iidx, const float* __restrict__ im,
    const int* __restrict__ oidx, const float* __restrict__ om,
    const int* __restrict__ ie, const int* __restrict__ oe,
    _Float16* __restrict__ X) {
  const int half = lane >> 5;
  const int lc = lane & 31;
  const int sel = lane >> 4, p16 = lane & 15;

  const int bb = row * Kn + p16;
  const int* ap = (sel == 0)   ? (iidx + bb)
                  : (sel == 1) ? ((const int*)im + bb)
                  : (sel == 2) ? (oidx + bb)
                               : ((const int*)om + bb);
  const int cmb = *ap;
  const int cmbe = *(((lane & 16) ? oe : ie) + bb);

  const int hb = row & ~511;
  const float* hp = node_reps + ((size_t)hb << 8) + (lc << 3);

  float acc[8] = {};
#pragma unroll
  for (int kb = 0; kb < 2; kb++) {
    f4 w0[8], w1[8];
#pragma unroll
    for (int k = 0; k < 8; k++) {
      const int ik = __shfl(cmb, (lane & 32) | (kb * 8 + k), 64);
      const float* p = hp + ((size_t)ik << 8);
      w0[k] = *(const f4*)p;
      w1[k] = *(const f4*)(p + 4);
    }
    __builtin_amdgcn_sched_barrier(0);
#pragma unroll
    for (int k = 0; k < 8; k++) {
      const float mk = __int_as_float(__shfl(cmb, (lane & 32) | 16 | (kb * 8 + k), 64));
#pragma unroll
      for (int c = 0; c < 4; c++) {
        acc[c] += mk * w0[k][c];
        acc[4 + c] += mk * w1[k][c];
      }
    }
  }
  {
    float b0 = 0.f, b1 = 0.f;
    const int vmine = 2 * lane - half * 64;
#pragma unroll
    for (int k = 0; k < 16; k++) {
      const int ec = __shfl(cmbe, (half << 4) | k, 64);
      const float mc = __int_as_float(__shfl(cmb, (lane & 32) | 16 | k, 64));
      b0 += (ec == vmine) ? mc : 0.f;
      b1 += (ec == vmine + 1) ? mc : 0.f;
    }
    h2 bp;
    bp[0] = (_Float16)b0;
    bp[1] = (_Float16)b1;
    *(h2*)&X[(size_t)row * NC + 512 + lane * 2] = bp;
  }
  h8 o;
#pragma unroll
  for (int c = 0; c < 8; c++) o[c] = (_Float16)acc[c];
  *(h8*)&X[(size_t)row * NC + half * 256 + lc * 8] = o;
}

// agg1 single row: fp16 delta gathers -> X cols [0,512).
__device__ __forceinline__ void agg1_row(int row, int lane,
    const _Float16* __restrict__ src,
    const int* __restrict__ iidx, const float* __restrict__ im,
    const int* __restrict__ oidx, const float* __restrict__ om,
    _Float16* __restrict__ X) {
  const int half = lane >> 5;
  const int lc = lane & 31;
  const int sel = lane >> 4, p16 = lane & 15;

  const int bb = row * Kn + p16;
  const int* ap = (sel == 0)   ? (iidx + bb)
                  : (sel == 1) ? ((const int*)im + bb)
                  : (sel == 2) ? (oidx + bb)
                               : ((const int*)om + bb);
  const int cmb = *ap;

  const int hb = row & ~511;
  const _Float16* hp = src + ((size_t)hb << 8) + (lc << 3);

  h8 w[16];
#pragma unroll
  for (int k = 0; k < 16; k++) {
    const int ik = __shfl(cmb, (lane & 32) | k, 64);
    w[k] = *(const h8*)(hp + ((size_t)ik << 8));
  }
  __builtin_amdgcn_sched_barrier(0);

  float acc[8] = {};
#pragma unroll
  for (int k = 0; k < 16; k++) {
    const float mk = __int_as_float(__shfl(cmb, (lane & 32) | 16 | k, 64));
#pragma unroll
    for (int c = 0; c < 8; c++) acc[c] += mk * (float)w[k][c];
  }
  h8 o;
#pragma unroll
  for (int c = 0; c < 8; c++) o[c] = (_Float16)acc[c];
  *(h8*)&X[(size_t)row * NC + half * 256 + lc * 8] = o;
}

// 4-wave MFMA GEMM + fused LSTM (R13 structure), as a device body.
template <bool WITH_Z>
__device__ __forceinline__ void gemm_body(
    _Float16 (&lds)[3][8192], int blk, int tid,
    const _Float16* __restrict__ A, const _Float16* __restrict__ Wf,
    const float* __restrict__ biasq, _Float16* __restrict__ zq,
    const float* __restrict__ mask, const float* __restrict__ node_reps,
    float* __restrict__ reps, float* __restrict__ hbuf,
    _Float16* __restrict__ d16, float* __restrict__ cbuf) {
  constexpr int KT = WITH_Z ? 20 : 16;
  constexpr int D = 4;

  const int wg = (blk & 7) * 64 + (blk >> 3);  // XCD swizzle
  const int bm = wg >> 3, bn = wg & 7;
  const int lane = tid & 63, wid = tid >> 6;
  const int wr = wid >> 1, wc = wid & 1;
  const int lr = lane & 15, lg = lane >> 4;

  f4 acc[4][4] = {};

  const _Float16* srcA0 = A + (size_t)(bm * 128 + 2 * wid * 16 + lr) * NC + lg * 8;
  const _Float16* srcB0 = Wf + ((size_t)bn * 8 + 2 * wid) * 512 + lane * 8;
  const int woff = 2 * wid * 512;

  auto stage = [&](int buf, int kt) {
    _Float16* base = lds[buf];
    const _Float16* sa = srcA0 + kt * 32;
    gload16(base + woff, sa);
    gload16(base + woff + 512, sa + 16 * NC);
    const _Float16* sb = srcB0 + (size_t)kt * 32768;
    gload16(base + 4096 + woff, sb);
    gload16(base + 4096 + woff + 512, sb + 512);
  };

  stage(0, 0);
  stage(1, 1);
  asm volatile("s_waitcnt vmcnt(%0)" :: "i"(D) : "memory");
  __builtin_amdgcn_s_barrier();

  int cur = 0;
  for (int kt = 0; kt < KT; kt++) {
    if (kt + 2 < KT) stage(cur == 0 ? 2 : cur - 1, kt + 2);

    const _Float16* base = lds[cur];
    h8 a[4], bfr[4];
#pragma unroll
    for (int m = 0; m < 4; m++) a[m] = *(const h8*)&base[(wr * 4 + m) * 512 + lane * 8];
#pragma unroll
    for (int n = 0; n < 4; n++) bfr[n] = *(const h8*)&base[4096 + (wc * 4 + n) * 512 + lane * 8];
    asm volatile("s_waitcnt lgkmcnt(0)" ::: "memory");
    __builtin_amdgcn_sched_barrier(0);

    __builtin_amdgcn_s_setprio(1);
#pragma unroll
    for (int m = 0; m < 4; m++)
#pragma unroll
      for (int n = 0; n < 4; n++)
        acc[m][n] = __builtin_amdgcn_mfma_f32_16x16x32_f16(a[m], bfr[n], acc[m][n], 0, 0, 0);
    __builtin_amdgcn_s_setprio(0);

    if (kt + 2 < KT) asm volatile("s_waitcnt vmcnt(%0)" :: "i"(D) : "memory");
    else             asm volatile("s_waitcnt vmcnt(0)" ::: "memory");
    __builtin_amdgcn_sched_barrier(0);
    __builtin_amdgcn_s_barrier();

    cur = (cur == 2) ? 0 : cur + 1;
  }

  const int d = (bn * 2 + wc) * 16 + lr;
  const int row0 = bm * 128 + wr * 64;
  f4 bq = {0.f, 0.f, 0.f, 0.f};
  if (WITH_Z) bq = *(const f4*)&biasq[d * 4];
#pragma unroll
  for (int i = 0; i < 4; i++) {
#pragma unroll
    for (int r = 0; r < 4; r++) {
      const int row = row0 + i * 16 + lg * 4 + r;
      const size_t off = (size_t)row * Dd + d;
      float zi, zf, zo, zc;
      if (WITH_Z) {
        zi = acc[i][0][r] + bq.x;
        zf = acc[i][1][r] + bq.y;
        zo = acc[i][2][r] + bq.z;
        zc = acc[i][3][r] + bq.w;
        h4 oz;
        oz[0] = (_Float16)zi; oz[1] = (_Float16)zf;
        oz[2] = (_Float16)zo; oz[3] = (_Float16)zc;
        *(h4*)&zq[off * 4] = oz;
      } else {
        const h4 zb = *(const h4*)&zq[off * 4];
        zi = (float)zb[0] + acc[i][0][r];
        zf = (float)zb[1] + acc[i][1][r];
        zo = (float)zb[2] + acc[i][2][r];
        zc = (float)zb[3] + acc[i][3][r];
      }
      const float ig = fsigm(zi), fg = fsigm(zf), og = fsigm(zo), ci = ftanh(zc);
      const float cold = WITH_Z ? 0.f : cbuf[off];
      const float cn = fg * cold + ig * ci;
      const float hn = og * ftanh(cn);
      const float mk = mask[row];
      cbuf[off] = cn * mk;
      const float hm = hn * mk;
      reps[off] = hm;
      if (WITH_Z) d16[off] = (_Float16)(hm - node_reps[off]);
      else        hbuf[off] = hm;
    }
  }
}

// ---------------------------------------------------------------------------
// Cooperative all-in-one: 512 blocks x 256 threads, 2 blocks/CU guaranteed.
// Phase 1: P/fold/bias (blocks 0..160) + agg0 (all blocks, 4 rows/wave)
// Phase 2: gemm0 (K=640) + LSTM0  -> zq, reps0, d16, cbuf
// Phase 3: agg1 (delta gathers)
// Phase 4: gemm1 (K=512) + LSTM1  -> reps1, hbuf, cbuf
// ---------------------------------------------------------------------------
__global__ __launch_bounds__(256, 2) void grn_all(
    const float* __restrict__ node_reps, const float* __restrict__ mask,
    const int* __restrict__ iidx, const float* __restrict__ im,
    const int* __restrict__ oidx, const float* __restrict__ om,
    const int* __restrict__ ie, const int* __restrict__ oe,
    const float* __restrict__ emb,
    const float* __restrict__ Wi, const float* __restrict__ Wo,
    const float* __restrict__ Ui, const float* __restrict__ Uo,
    const float* __restrict__ bi, const float* __restrict__ bo,
    const float* __restrict__ bui, const float* __restrict__ buo,
    _Float16* __restrict__ X, _Float16* __restrict__ W0f,
    _Float16* __restrict__ Wlf, float* __restrict__ biasq,
    _Float16* __restrict__ zq, _Float16* __restrict__ d16,
    float* __restrict__ reps0, float* __restrict__ reps1,
    float* __restrict__ hbuf, float* __restrict__ cbuf) {
  __shared__ __align__(16) _Float16 lds[3][8192];  // 48 KB
  cg::grid_group grid = cg::this_grid();
  const int b = blockIdx.x, t = threadIdx.x;
  const int lane = t & 63, wid = t >> 6;
  const int xcd = b & 7, grp = b >> 3;

  // ---- Phase 1: weight roles + agg0 ----
  if (b < 128) {
    role_P(b, t, (char*)lds, emb, Wi, Wo, Ui, Uo, W0f);
    __syncthreads();
  } else if (b < 160) {
    role_fold(b - 128, t, Wi, Wo, Ui, Uo, W0f, Wlf);
  } else if (b == 160) {
#pragma unroll
    for (int i = 0; i < 4; i++) {
      const int cq = t * 4 + i;
      const int dd = cq >> 2, g = cq & 3;
      const int c = g * 256 + dd;
      biasq[cq] = bi[c] + bo[c] + bui[c] + buo[c];
    }
  }
#pragma unroll
  for (int j = 0; j < 4; j++) {
    const int row = xcd * 1024 + grp * 16 + wid * 4 + j;
    agg0_row(row, lane, node_reps, iidx, im, oidx, om, ie, oe, X);
  }

  __threadfence();
  grid.sync();

  // ---- Phase 2: gemm0 + LSTM0 ----
  gemm_body<true>(lds, b, t, X, W0f, biasq, zq, mask, node_reps,
                  reps0, nullptr, d16, cbuf);

  __threadfence();
  grid.sync();

  // ---- Phase 3: agg1 ----
#pragma unroll
  for (int j = 0; j < 4; j++) {
    const int row = xcd * 1024 + grp * 16 + wid * 4 + j;
    agg1_row(row, lane, d16, iidx, im, oidx, om, X);
  }

  __threadfence();
  grid.sync();

  // ---- Phase 4: gemm1 + LSTM1 ----
  gemm_body<false>(lds, b, t, X, Wlf, biasq, zq, mask, nullptr,
                   reps1, hbuf, nullptr, cbuf);
}

// ---------------------------------------------------------------------------
// Fallback path (R15 kernels, verbatim behavior)
// ---------------------------------------------------------------------------
__global__ __launch_bounds__(256, 4) void mega2_kernel(
    const float* __restrict__ node_reps, const float* __restrict__ emb,
    const int* __restrict__ iidx, const float* __restrict__ im,
    const int* __restrict__ oidx, const float* __restrict__ om,
    const int* __restrict__ ie, const int* __restrict__ oe,
    const float* __restrict__ Wi, const float* __restrict__ Wo,
    const float* __restrict__ Ui, const float* __restrict__ Uo,
    const float* __restrict__ bi, const float* __restrict__ bo,
    const float* __restrict__ bui, const float* __restrict__ buo,
    _Float16* __restrict__ X, _Float16* __restrict__ W0f,
    _Float16* __restrict__ Wlf, float* __restrict__ biasq) {
  __shared__ __align__(16) char smem[20480];
  const int b = blockIdx.x, t = threadIdx.x;
  if (b < 2048) {
    const int lane = t & 63, wid = t >> 6;
    const int row = (b & 7) * 1024 + (b >> 3) * 4 + wid;
    agg0_row(row, lane, node_reps, iidx, im, oidx, om, ie, oe, X);
  } else if (b < 2176) {
    role_P(b - 2048, t, smem, emb, Wi, Wo, Ui, Uo, W0f);
  } else if (b < 2208) {
    role_fold(b - 2176, t, Wi, Wo, Ui, Uo, W0f, Wlf);
  } else {
#pragma unroll
    for (int i = 0; i < 4; i++) {
      const int cq = t * 4 + i;
      const int dd = cq >> 2, g = cq & 3;
      const int c = g * 256 + dd;
      biasq[cq] = bi[c] + bo[c] + bui[c] + buo[c];
    }
  }
}

__global__ __launch_bounds__(256, 4) void agg1_kernel(
    const _Float16* __restrict__ src,
    const int* __restrict__ iidx, const float* __restrict__ im,
    const int* __restrict__ oidx, const float* __restrict__ om,
    _Float16* __restrict__ X) {
  const int lane = threadIdx.x & 63;
  const int wid = threadIdx.x >> 6;
  const int b = blockIdx.x;
  const int row = (b & 7) * 1024 + (b >> 3) * 4 + wid;
  agg1_row(row, lane, src, iidx, im, oidx, om, X);
}

template <bool WITH_Z>
__global__ __launch_bounds__(256) void fused_gemm(
    const _Float16* __restrict__ A, const _Float16* __restrict__ Wf,
    const float* __restrict__ biasq, _Float16* __restrict__ zq,
    const float* __restrict__ mask, const float* __restrict__ node_reps,
    float* __restrict__ reps, float* __restrict__ hbuf,
    _Float16* __restrict__ d16, float* __restrict__ cbuf) {
  __shared__ __align__(16) _Float16 lds[3][8192];
  gemm_body<WITH_Z>(lds, blockIdx.x, threadIdx.x, A, Wf, biasq, zq, mask,
                    node_reps, reps, hbuf, d16, cbuf);
}

// ---------------------------------------------------------------------------
extern "C" void kernel_launch(void* const* d_in, const int* in_sizes, int n_in,
                              void* d_out, int out_size, void* d_ws, size_t ws_size,
                              hipStream_t stream) {
  const float* node_reps = (const float*)d_in[0];
  const float* mask      = (const float*)d_in[1];
  const int*   in_idx    = (const int*)d_in[2];
  const int*   in_edges  = (const int*)d_in[3];
  const float* in_mask   = (const float*)d_in[4];
  const int*   out_idx   = (const int*)d_in[5];
  const int*   out_edges = (const int*)d_in[6];
  const float* out_mask  = (const float*)d_in[7];
  const float* edge_emb  = (const float*)d_in[8];
  const float* Wi  = (const float*)d_in[9];
  const float* Wo  = (const float*)d_in[10];
  const float* Ui  = (const float*)d_in[11];
  const float* Uo  = (const float*)d_in[12];
  const float* bi  = (const float*)d_in[13];
  const float* bo  = (const float*)d_in[14];
  const float* bui = (const float*)d_in[15];
  const float* buo = (const float*)d_in[16];

  float* out = (float*)d_out;
  const size_t MD = (size_t)MR * Dd;
  float* reps0 = out;
  float* reps1 = out + MD;
  float* hbuf  = out + 2 * MD;
  float* cbuf  = out + 3 * MD;

  _Float16* X    = (_Float16*)d_ws;                 // 16 MB
  _Float16* zq   = X + (size_t)MR * NC;             // 16 MB
  _Float16* W0f  = zq + (size_t)MR * NC;            // 640*1024 (1.25 MB)
  _Float16* Wlf  = W0f + 640 * 1024;                // 512*1024 (1 MB)
  _Float16* d16  = Wlf + 512 * 1024;                // 4 MB
  float*    biasq = (float*)(d16 + (size_t)MR * Dd);

  void* args[] = {
      (void*)&node_reps, (void*)&mask,
      (void*)&in_idx, (void*)&in_mask, (void*)&out_idx, (void*)&out_mask,
      (void*)&in_edges, (void*)&out_edges, (void*)&edge_emb,
      (void*)&Wi, (void*)&Wo, (void*)&Ui, (void*)&Uo,
      (void*)&bi, (void*)&bo, (void*)&bui, (void*)&buo,
      (void*)&X, (void*)&W0f, (void*)&Wlf, (void*)&biasq,
      (void*)&zq, (void*)&d16,
      (void*)&reps0, (void*)&reps1, (void*)&hbuf, (void*)&cbuf};

  hipError_t e = hipLaunchCooperativeKernel((const void*)grn_all, dim3(512),
                                            dim3(256), args, 0, stream);
  if (e != hipSuccess) {
    (void)hipGetLastError();  // clear error state; use proven 4-kernel path
    mega2_kernel<<<2209, 256, 0, stream>>>(
        node_reps, edge_emb, in_idx, in_mask, out_idx, out_mask, in_edges,
        out_edges, Wi, Wo, Ui, Uo, bi, bo, bui, buo, X, W0f, Wlf, biasq);
    fused_gemm<true><<<512, 256, 0, stream>>>(
        X, W0f, biasq, zq, mask, node_reps, reps0, nullptr, d16, cbuf);
    agg1_kernel<<<2048, 256, 0, stream>>>(d16, in_idx, in_mask, out_idx,
                                          out_mask, X);
    fused_gemm<false><<<512, 256, 0, stream>>>(
        X, Wlf, nullptr, zq, mask, nullptr, reps1, hbuf, nullptr, cbuf);
  }
}

// Round 17
// 75.485 us; speedup vs baseline: 5.7156x; 5.7156x over previous
//
#include <hip/hip_runtime.h>
#include <math.h>

// (B,N,K,D,V,L) = (16,512,16,256,64,2)
#define Kn 16
#define Dd 256
#define NC 1024
#define XS 640   // compacted X row stride (512 Nh + 128 bins)
#define MR 8192

typedef _Float16 h8 __attribute__((ext_vector_type(8)));
typedef _Float16 h4 __attribute__((ext_vector_type(4)));
typedef _Float16 h2 __attribute__((ext_vector_type(2)));
typedef float f4 __attribute__((ext_vector_type(4)));

__device__ __forceinline__ void gload16(_Float16* lds, const _Float16* g) {
  __builtin_amdgcn_global_load_lds(
      (const __attribute__((address_space(1))) void*)g,
      (__attribute__((address_space(3))) void*)lds, 16, 0, 0);
}

__device__ __forceinline__ float fsigm(float x) { return 1.f / (1.f + __expf(-x)); }
__device__ __forceinline__ float ftanh(float x) { return 2.f / (1.f + __expf(-2.f * x)) - 1.f; }

// ---------------------------------------------------------------------------
// mega2: role-split grid (2209 blocks):
//   [0,2048):     agg0 — 1 row/wave, XCD-contiguous rows, f32 gathers
//                 (batched 16-in-flight) + inline edge bins -> X (stride 640)
//   [2048,2176):  P = emb @ (W+U)bottom -> W0f fragment rows k=512+vv
//   [2176,2208):  fold: W0'top = (W+U)_top -> W0f; Wl = U_top (f4 batched)
//   2208:         biasq
// Fragment: Wf[kt][nt][lane][j], k = kt*32+(lane>>4)*8+j, cp = nt*16+(lane&15)
// col perm:  cp = 64*(d>>4)+16*g+(d&15)  <->  c = g*256+d
// ---------------------------------------------------------------------------
__global__ __launch_bounds__(256, 4) void mega2_kernel(
    const float* __restrict__ node_reps, const float* __restrict__ emb,
    const int* __restrict__ iidx, const float* __restrict__ im,
    const int* __restrict__ oidx, const float* __restrict__ om,
    const int* __restrict__ ie, const int* __restrict__ oe,
    const float* __restrict__ Wi, const float* __restrict__ Wo,
    const float* __restrict__ Ui, const float* __restrict__ Uo,
    const float* __restrict__ bi, const float* __restrict__ bo,
    const float* __restrict__ bui, const float* __restrict__ buo,
    _Float16* __restrict__ X, _Float16* __restrict__ W0f,
    _Float16* __restrict__ Wlf, float* __restrict__ biasq) {
  __shared__ __align__(16) char smem[20480];
  const int b = blockIdx.x, t = threadIdx.x;

  if (b < 2048) {
    // ---- role agg0: one row/wave, f32 gathers + inline bins ----
    const int lane = t & 63;
    const int wid = t >> 6;
    const int row = (b & 7) * 1024 + (b >> 3) * 4 + wid;  // XCD-contiguous
    const int half = lane >> 5;
    const int lc = lane & 31;
    const int sel = lane >> 4, p16 = lane & 15;

    const int bb = row * Kn + p16;
    const int* ap = (sel == 0)   ? (iidx + bb)
                    : (sel == 1) ? ((const int*)im + bb)
                    : (sel == 2) ? (oidx + bb)
                                 : ((const int*)om + bb);
    const int cmb = *ap;
    const int cmbe = *(((lane & 16) ? oe : ie) + bb);

    const int hb = row & ~511;
    const float* hp = node_reps + ((size_t)hb << 8) + (lc << 3);

    float acc[8] = {};
#pragma unroll
    for (int kb = 0; kb < 2; kb++) {
      f4 w0[8], w1[8];
#pragma unroll
      for (int k = 0; k < 8; k++) {  // 16 loads in flight
        const int ik = __shfl(cmb, (lane & 32) | (kb * 8 + k), 64);
        const float* p = hp + ((size_t)ik << 8);
        w0[k] = *(const f4*)p;
        w1[k] = *(const f4*)(p + 4);
      }
      __builtin_amdgcn_sched_barrier(0);  // keep gather issue above consume
#pragma unroll
      for (int k = 0; k < 8; k++) {
        const float mk = __int_as_float(__shfl(cmb, (lane & 32) | 16 | (kb * 8 + k), 64));
#pragma unroll
        for (int c = 0; c < 4; c++) {
          acc[c] += mk * w0[k][c];
          acc[4 + c] += mk * w1[k][c];
        }
      }
    }

    {  // edge bins (reuses cmb/cmbe; no gathers)
      float b0 = 0.f, b1 = 0.f;
      const int vmine = 2 * lane - half * 64;
#pragma unroll
      for (int k = 0; k < 16; k++) {
        const int ec = __shfl(cmbe, (half << 4) | k, 64);
        const float mc = __int_as_float(__shfl(cmb, (lane & 32) | 16 | k, 64));
        b0 += (ec == vmine) ? mc : 0.f;
        b1 += (ec == vmine + 1) ? mc : 0.f;
      }
      h2 bp;
      bp[0] = (_Float16)b0;
      bp[1] = (_Float16)b1;
      *(h2*)&X[(size_t)row * XS + 512 + lane * 2] = bp;
    }

    h8 o;
#pragma unroll
    for (int c = 0; c < 8; c++) o[c] = (_Float16)acc[c];
    *(h8*)&X[(size_t)row * XS + half * 256 + lc * 8] = o;
  } else if (b < 2176) {
    // ---- role P: 4 vv per block, quarter cq of columns ----
    float* seT = (float*)smem;             // [256 dd][4 r] f32 (4 KB)
    float* sa = (float*)(smem + 4096);     // [4 ds][4 r][64 l] f4 (16 KB)
    const int pb = b - 2048;
    const int vgrp = pb >> 2, cq = pb & 3;
    const int dir = vgrp >> 4;
    const int v0 = (vgrp & 15) * 4;        // emb row base within dir
    const float* Wa = dir ? Wo : Wi;
    const float* Ua = dir ? Uo : Ui;
#pragma unroll
    for (int r = 0; r < 4; r++) seT[t * 4 + r] = emb[(v0 + r) * 256 + t];
    __syncthreads();

    const int l = t & 63, ds = t >> 6;
    const int cp0 = cq * 256 + l * 4;
    const int g = (cp0 >> 4) & 3;
    const int d0 = ((cp0 >> 6) << 4) + (cp0 & 15);
    const int c0 = g * 256 + d0;
    const float* wp = Wa + (size_t)(256 + ds * 64) * NC + c0;
    const float* up = Ua + (size_t)(256 + ds * 64) * NC + c0;
    const float* sT = seT + (ds * 64) * 4;

    f4 av[4] = {};
    for (int bb8 = 0; bb8 < 8; bb8++) {
      f4 wv8[8], uv8[8];
#pragma unroll
      for (int ii = 0; ii < 8; ii++) {  // 16 loads in flight
        const int dd = bb8 * 8 + ii;
        wv8[ii] = *(const f4*)(wp + (size_t)dd * NC);
        uv8[ii] = *(const f4*)(up + (size_t)dd * NC);
      }
      __builtin_amdgcn_sched_barrier(0);
#pragma unroll
      for (int ii = 0; ii < 8; ii++) {
        const int dd = bb8 * 8 + ii;
        const f4 wv = wv8[ii] + uv8[ii];
        const f4 s0 = *(const f4*)&sT[dd * 4];  // wave-uniform: broadcast
        av[0] += s0[0] * wv;
        av[1] += s0[1] * wv;
        av[2] += s0[2] * wv;
        av[3] += s0[3] * wv;
      }
    }
#pragma unroll
    for (int r = 0; r < 4; r++) *(f4*)&sa[((ds * 4 + r) * 64 + l) * 4] = av[r];
    __syncthreads();
    {
      const int r = t >> 6, fl = t & 63;   // 256 items: (r, l)
      f4 s = {0.f, 0.f, 0.f, 0.f};
#pragma unroll
      for (int d = 0; d < 4; d++) s += *(const f4*)&sa[((d * 4 + r) * 64 + fl) * 4];
      const int vvg = vgrp * 4 + r;
      const int kt = 16 + (vvg >> 5);
      const int lhi = (vvg >> 3) & 3;
      const int j = vvg & 7;
      const int cpb = cq * 256 + fl * 4;
#pragma unroll
      for (int i = 0; i < 4; i++) {
        const int cp = cpb + i;
        W0f[kt * 32768 + (cp >> 4) * 512 + (lhi * 16 + (cp & 15)) * 8 + j] = (_Float16)s[i];
      }
    }
  } else if (b < 2208) {
    // ---- role fold: coalesced f4 loads (batched), permuted scatter stores
    const int p = b - 2176;         // 0..15 -> W0f kt=p ; 16..31 -> Wlf kt=p-16
    const int kk = t >> 3;          // k within plane, 0..31
    const int tc = t & 7;           // column subgroup
    const int k = (p & 15) * 32 + kk;
    const float* rowp;
    const float* rowp2 = nullptr;
    if (p < 16) {
      rowp  = (k < 256) ? Wi + (size_t)k * NC : Wo + (size_t)(k - 256) * NC;
      rowp2 = (k < 256) ? Ui + (size_t)k * NC : Uo + (size_t)(k - 256) * NC;
    } else {
      rowp  = (k < 256) ? Ui + (size_t)k * NC : Uo + (size_t)(k - 256) * NC;
    }
    _Float16* dst = (p < 16) ? (W0f + p * 32768) : (Wlf + (p - 16) * 32768);
    const int lane0 = (kk >> 3) * 16;
    const int j = kk & 7;
    for (int bb8 = 0; bb8 < 4; bb8++) {
      f4 w8[8], u8[8];
#pragma unroll
      for (int ii = 0; ii < 8; ii++) {  // 8-16 loads in flight
        const int c = (bb8 * 8 + ii) * 32 + tc * 4;
        w8[ii] = *(const f4*)(rowp + c);
        if (p < 16) u8[ii] = *(const f4*)(rowp2 + c);
      }
      __builtin_amdgcn_sched_barrier(0);
#pragma unroll
      for (int ii = 0; ii < 8; ii++) {
        const int c = (bb8 * 8 + ii) * 32 + tc * 4;
        const int g = c >> 8, d = c & 255;
        const int nt = 4 * (d >> 4) + g;
        const int lb = lane0 + (d & 15);
        f4 v = w8[ii];
        if (p < 16) v += u8[ii];
#pragma unroll
        for (int q = 0; q < 4; q++)
          dst[nt * 512 + (lb + q) * 8 + j] = (_Float16)v[q];
      }
    }
  } else {
    // ---- role bias ----
#pragma unroll
    for (int i = 0; i < 4; i++) {
      const int cq = t * 4 + i;
      const int dd = cq >> 2, g = cq & 3;
      const int c = g * 256 + dd;
      biasq[cq] = bi[c] + bo[c] + bui[c] + buo[c];
    }
  }
}

// ---------------------------------------------------------------------------
// Iter-1 gather-aggregate: d16 fp16 [8192][256] -> X (stride 640) cols [0,512).
// One row per wave, XCD-contiguous stripes, 16 h8 gathers in flight.
// ---------------------------------------------------------------------------
__global__ __launch_bounds__(256, 4) void agg_kernel(
    const _Float16* __restrict__ src,
    const int* __restrict__ iidx, const float* __restrict__ im,
    const int* __restrict__ oidx, const float* __restrict__ om,
    _Float16* __restrict__ X) {
  const int lane = threadIdx.x & 63;
  const int wid = threadIdx.x >> 6;
  const int b = blockIdx.x;
  const int row = (b & 7) * 1024 + (b >> 3) * 4 + wid;  // XCD-contiguous
  const int half = lane >> 5;
  const int lc = lane & 31;
  const int sel = lane >> 4, p16 = lane & 15;

  const int bb = row * Kn + p16;
  const int* ap = (sel == 0)   ? (iidx + bb)
                  : (sel == 1) ? ((const int*)im + bb)
                  : (sel == 2) ? (oidx + bb)
                               : ((const int*)om + bb);
  const int cmb = *ap;

  const int hb = row & ~511;
  const _Float16* hp = src + ((size_t)hb << 8) + (lc << 3);

  h8 w[16];
#pragma unroll
  for (int k = 0; k < 16; k++) {  // 16 x 16B loads in flight
    const int ik = __shfl(cmb, (lane & 32) | k, 64);
    w[k] = *(const h8*)(hp + ((size_t)ik << 8));
  }
  __builtin_amdgcn_sched_barrier(0);  // keep gather issue above consume

  float acc[8] = {};
#pragma unroll
  for (int k = 0; k < 16; k++) {
    const float mk = __int_as_float(__shfl(cmb, (lane & 32) | 16 | k, 64));
#pragma unroll
    for (int c = 0; c < 8; c++) acc[c] += mk * (float)w[k][c];
  }

  h8 o;
#pragma unroll
  for (int c = 0; c < 8; c++) o[c] = (_Float16)acc[c];
  *(h8*)&X[(size_t)row * XS + half * 256 + lc * 8] = o;
}

// ---------------------------------------------------------------------------
// Fused MFMA GEMM + LSTM, 8-wave (R15 structure). 128x128 tile, 512 threads,
// wave grid 4(M)x2(N): each wave 32 rows x 64 cols, acc[2][4], 8 MFMA/kt.
// 3-buffer counted-vmcnt pipeline (per-thread staging: 1 A + 1 B gload).
// A rows have stride XS=640 fp16.
//   WITH_Z (iter 0): B = W0' (K=640); z0 = acc + bias; zq = fp16(z0);
//     LSTM0 (c=0) -> reps0, cbuf; d16 = fp16(h1 - node_reps).
//   !WITH_Z (iter 1): B = Wl (K=512), A = Delta; z1 = zq + acc;
//     LSTM1 -> reps1, hbuf, cbuf.
// ---------------------------------------------------------------------------
template <bool WITH_Z>
__global__ __launch_bounds__(512) void fused_gemm(
    const _Float16* __restrict__ A, const _Float16* __restrict__ Wf,
    const float* __restrict__ biasq, _Float16* __restrict__ zq,
    const float* __restrict__ mask, const float* __restrict__ node_reps,
    float* __restrict__ reps, float* __restrict__ hbuf,
    _Float16* __restrict__ d16, float* __restrict__ cbuf) {
  constexpr int KT = WITH_Z ? 20 : 16;
  constexpr int D = 2;  // gloads per stage per THREAD (A + B)
  __shared__ __align__(16) _Float16 lds[3][8192];  // 48 KB

  const int wg = (blockIdx.x & 7) * 64 + (blockIdx.x >> 3);  // XCD swizzle
  const int bm = wg >> 3, bn = wg & 7;
  const int tid = threadIdx.x, lane = tid & 63, wid = tid >> 6;  // wid 0..7
  const int wr = wid >> 1, wc = wid & 1;   // 4x2 wave grid
  const int lr = lane & 15, lg = lane >> 4;

  f4 acc[2][4] = {};

  // per-wave staging: wave wid stages A frag-row wid and B frag wid
  const _Float16* srcA0 = A + (size_t)(bm * 128 + wid * 16 + lr) * XS + lg * 8;
  const _Float16* srcB0 = Wf + ((size_t)bn * 8 + wid) * 512 + lane * 8;
  const int woff = wid * 512;

  auto stage = [&](int buf, int kt) {
    _Float16* base = lds[buf];
    gload16(base + woff, srcA0 + kt * 32);
    gload16(base + 4096 + woff, srcB0 + (size_t)kt * 32768);
  };

  stage(0, 0);
  stage(1, 1);
  asm volatile("s_waitcnt vmcnt(%0)" :: "i"(D) : "memory");
  __builtin_amdgcn_s_barrier();

  int cur = 0;
  for (int kt = 0; kt < KT; kt++) {
    if (kt + 2 < KT) stage(cur == 0 ? 2 : cur - 1, kt + 2);

    const _Float16* base = lds[cur];
    h8 a[2], bfr[4];
#pragma unroll
    for (int m = 0; m < 2; m++) a[m] = *(const h8*)&base[(wr * 2 + m) * 512 + lane * 8];
#pragma unroll
    for (int n = 0; n < 4; n++) bfr[n] = *(const h8*)&base[4096 + (wc * 4 + n) * 512 + lane * 8];
    asm volatile("s_waitcnt lgkmcnt(0)" ::: "memory");
    __builtin_amdgcn_sched_barrier(0);

    __builtin_amdgcn_s_setprio(1);
#pragma unroll
    for (int m = 0; m < 2; m++)
#pragma unroll
      for (int n = 0; n < 4; n++)
        acc[m][n] = __builtin_amdgcn_mfma_f32_16x16x32_f16(a[m], bfr[n], acc[m][n], 0, 0, 0);
    __builtin_amdgcn_s_setprio(0);

    if (kt + 2 < KT) asm volatile("s_waitcnt vmcnt(%0)" :: "i"(D) : "memory");
    else             asm volatile("s_waitcnt vmcnt(0)" ::: "memory");
    __builtin_amdgcn_sched_barrier(0);
    __builtin_amdgcn_s_barrier();

    cur = (cur == 2) ? 0 : cur + 1;
  }

  // epilogue: n-fragment index == gate g; lane lr picks output dim
  const int d = (bn * 2 + wc) * 16 + lr;
  const int row0 = bm * 128 + wr * 32;
  f4 bq = {0.f, 0.f, 0.f, 0.f};
  if (WITH_Z) bq = *(const f4*)&biasq[d * 4];
#pragma unroll
  for (int i = 0; i < 2; i++) {
#pragma unroll
    for (int r = 0; r < 4; r++) {
      const int row = row0 + i * 16 + lg * 4 + r;
      const size_t off = (size_t)row * Dd + d;
      float zi, zf, zo, zc;
      if (WITH_Z) {
        zi = acc[i][0][r] + bq.x;
        zf = acc[i][1][r] + bq.y;
        zo = acc[i][2][r] + bq.z;
        zc = acc[i][3][r] + bq.w;
        h4 oz;
        oz[0] = (_Float16)zi; oz[1] = (_Float16)zf;
        oz[2] = (_Float16)zo; oz[3] = (_Float16)zc;
        *(h4*)&zq[off * 4] = oz;
      } else {
        const h4 zb = *(const h4*)&zq[off * 4];
        zi = (float)zb[0] + acc[i][0][r];
        zf = (float)zb[1] + acc[i][1][r];
        zo = (float)zb[2] + acc[i][2][r];
        zc = (float)zb[3] + acc[i][3][r];
      }
      const float ig = fsigm(zi), fg = fsigm(zf), og = fsigm(zo), ci = ftanh(zc);
      const float cold = WITH_Z ? 0.f : cbuf[off];
      const float cn = fg * cold + ig * ci;
      const float hn = og * ftanh(cn);
      const float mk = mask[row];
      cbuf[off] = cn * mk;
      const float hm = hn * mk;
      reps[off] = hm;
      if (WITH_Z) d16[off] = (_Float16)(hm - node_reps[off]);  // delta for agg1
      else        hbuf[off] = hm;                              // final h output
    }
  }
}

// ---------------------------------------------------------------------------
extern "C" void kernel_launch(void* const* d_in, const int* in_sizes, int n_in,
                              void* d_out, int out_size, void* d_ws, size_t ws_size,
                              hipStream_t stream) {
  const float* node_reps = (const float*)d_in[0];
  const float* mask      = (const float*)d_in[1];
  const int*   in_idx    = (const int*)d_in[2];
  const int*   in_edges  = (const int*)d_in[3];
  const float* in_mask   = (const float*)d_in[4];
  const int*   out_idx   = (const int*)d_in[5];
  const int*   out_edges = (const int*)d_in[6];
  const float* out_mask  = (const float*)d_in[7];
  const float* edge_emb  = (const float*)d_in[8];
  const float* Wi  = (const float*)d_in[9];
  const float* Wo  = (const float*)d_in[10];
  const float* Ui  = (const float*)d_in[11];
  const float* Uo  = (const float*)d_in[12];
  const float* bi  = (const float*)d_in[13];
  const float* bo  = (const float*)d_in[14];
  const float* bui = (const float*)d_in[15];
  const float* buo = (const float*)d_in[16];

  float* out = (float*)d_out;
  const size_t MD = (size_t)MR * Dd;
  float* reps0 = out;
  float* reps1 = out + MD;
  float* hbuf  = out + 2 * MD;
  float* cbuf  = out + 3 * MD;

  _Float16* X    = (_Float16*)d_ws;                 // 8192*640 fp16 (10.5 MB)
  _Float16* zq   = X + (size_t)MR * XS;             // 16 MB
  _Float16* W0f  = zq + (size_t)MR * NC;            // 640*1024 (1.25 MB)
  _Float16* Wlf  = W0f + 640 * 1024;                // 512*1024 (1 MB)
  _Float16* d16  = Wlf + 512 * 1024;                // 4 MB (fp16 delta)
  float*    biasq = (float*)(d16 + (size_t)MR * Dd);

  // 1. agg0(f32 gathers + bins) || P-GEMM || fold || bias
  mega2_kernel<<<2209, 256, 0, stream>>>(node_reps, edge_emb, in_idx, in_mask,
                                         out_idx, out_mask, in_edges, out_edges,
                                         Wi, Wo, Ui, Uo, bi, bo, bui, buo,
                                         X, W0f, Wlf, biasq);
  // 2. gemm0 (8-wave): z0 = X(K=640) @ W0' + bias; zq; LSTM0; d16 = h1-h0
  fused_gemm<true><<<512, 512, 0, stream>>>(
      X, W0f, biasq, zq, mask, node_reps, reps0, nullptr, d16, cbuf);
  // 3. agg1: gather fp16 delta -> X[:, :512)
  agg_kernel<<<2048, 256, 0, stream>>>(d16, in_idx, in_mask, out_idx, out_mask, X);
  // 4. gemm1 (8-wave): z1 = zq + Delta(K=512) @ Wl; LSTM1 -> final outputs
  fused_gemm<false><<<512, 512, 0, stream>>>(
      X, Wlf, nullptr, zq, mask, nullptr, reps1, hbuf, nullptr, cbuf);
}

// Round 18
// 72.204 us; speedup vs baseline: 5.9754x; 1.0454x over previous
//
#include <hip/hip_runtime.h>
#include <math.h>

// (B,N,K,D,V,L) = (16,512,16,256,64,2)
#define Kn 16
#define Dd 256
#define NC 1024
#define XS 640   // compacted X row stride (512 Nh + 128 bins)
#define MR 8192

typedef _Float16 h8 __attribute__((ext_vector_type(8)));
typedef _Float16 h4 __attribute__((ext_vector_type(4)));
typedef _Float16 h2 __attribute__((ext_vector_type(2)));
typedef float f4 __attribute__((ext_vector_type(4)));

__device__ __forceinline__ void gload16(_Float16* lds, const _Float16* g) {
  __builtin_amdgcn_global_load_lds(
      (const __attribute__((address_space(1))) void*)g,
      (__attribute__((address_space(3))) void*)lds, 16, 0, 0);
}

__device__ __forceinline__ float fsigm(float x) { return 1.f / (1.f + __expf(-x)); }
__device__ __forceinline__ float ftanh(float x) { return 2.f / (1.f + __expf(-2.f * x)) - 1.f; }

// ---------------------------------------------------------------------------
// mega2 (unchanged from R17): role-split grid (2209 blocks):
//   [0,2048):     agg0 — 1 row/wave, XCD-contiguous rows, f32 gathers
//                 (batched 16-in-flight) + inline edge bins -> X (stride 640)
//   [2048,2176):  P = emb @ (W+U)bottom -> W0f fragment rows k=512+vv
//   [2176,2208):  fold: W0'top = (W+U)_top -> W0f; Wl = U_top (f4 batched)
//   2208:         biasq
// Fragment: Wf[kt][nt][lane][j], k = kt*32+(lane>>4)*8+j, cp = nt*16+(lane&15)
// col perm:  cp = 64*(d>>4)+16*g+(d&15)  <->  c = g*256+d
// ---------------------------------------------------------------------------
__global__ __launch_bounds__(256, 4) void mega2_kernel(
    const float* __restrict__ node_reps, const float* __restrict__ emb,
    const int* __restrict__ iidx, const float* __restrict__ im,
    const int* __restrict__ oidx, const float* __restrict__ om,
    const int* __restrict__ ie, const int* __restrict__ oe,
    const float* __restrict__ Wi, const float* __restrict__ Wo,
    const float* __restrict__ Ui, const float* __restrict__ Uo,
    const float* __restrict__ bi, const float* __restrict__ bo,
    const float* __restrict__ bui, const float* __restrict__ buo,
    _Float16* __restrict__ X, _Float16* __restrict__ W0f,
    _Float16* __restrict__ Wlf, float* __restrict__ biasq) {
  __shared__ __align__(16) char smem[20480];
  const int b = blockIdx.x, t = threadIdx.x;

  if (b < 2048) {
    // ---- role agg0: one row/wave, f32 gathers + inline bins ----
    const int lane = t & 63;
    const int wid = t >> 6;
    const int row = (b & 7) * 1024 + (b >> 3) * 4 + wid;  // XCD-contiguous
    const int half = lane >> 5;
    const int lc = lane & 31;
    const int sel = lane >> 4, p16 = lane & 15;

    const int bb = row * Kn + p16;
    const int* ap = (sel == 0)   ? (iidx + bb)
                    : (sel == 1) ? ((const int*)im + bb)
                    : (sel == 2) ? (oidx + bb)
                                 : ((const int*)om + bb);
    const int cmb = *ap;
    const int cmbe = *(((lane & 16) ? oe : ie) + bb);

    const int hb = row & ~511;
    const float* hp = node_reps + ((size_t)hb << 8) + (lc << 3);

    float acc[8] = {};
#pragma unroll
    for (int kb = 0; kb < 2; kb++) {
      f4 w0[8], w1[8];
#pragma unroll
      for (int k = 0; k < 8; k++) {  // 16 loads in flight
        const int ik = __shfl(cmb, (lane & 32) | (kb * 8 + k), 64);
        const float* p = hp + ((size_t)ik << 8);
        w0[k] = *(const f4*)p;
        w1[k] = *(const f4*)(p + 4);
      }
      __builtin_amdgcn_sched_barrier(0);  // keep gather issue above consume
#pragma unroll
      for (int k = 0; k < 8; k++) {
        const float mk = __int_as_float(__shfl(cmb, (lane & 32) | 16 | (kb * 8 + k), 64));
#pragma unroll
        for (int c = 0; c < 4; c++) {
          acc[c] += mk * w0[k][c];
          acc[4 + c] += mk * w1[k][c];
        }
      }
    }

    {  // edge bins (reuses cmb/cmbe; no gathers)
      float b0 = 0.f, b1 = 0.f;
      const int vmine = 2 * lane - half * 64;
#pragma unroll
      for (int k = 0; k < 16; k++) {
        const int ec = __shfl(cmbe, (half << 4) | k, 64);
        const float mc = __int_as_float(__shfl(cmb, (lane & 32) | 16 | k, 64));
        b0 += (ec == vmine) ? mc : 0.f;
        b1 += (ec == vmine + 1) ? mc : 0.f;
      }
      h2 bp;
      bp[0] = (_Float16)b0;
      bp[1] = (_Float16)b1;
      *(h2*)&X[(size_t)row * XS + 512 + lane * 2] = bp;
    }

    h8 o;
#pragma unroll
    for (int c = 0; c < 8; c++) o[c] = (_Float16)acc[c];
    *(h8*)&X[(size_t)row * XS + half * 256 + lc * 8] = o;
  } else if (b < 2176) {
    // ---- role P: 4 vv per block, quarter cq of columns ----
    float* seT = (float*)smem;             // [256 dd][4 r] f32 (4 KB)
    float* sa = (float*)(smem + 4096);     // [4 ds][4 r][64 l] f4 (16 KB)
    const int pb = b - 2048;
    const int vgrp = pb >> 2, cq = pb & 3;
    const int dir = vgrp >> 4;
    const int v0 = (vgrp & 15) * 4;        // emb row base within dir
    const float* Wa = dir ? Wo : Wi;
    const float* Ua = dir ? Uo : Ui;
#pragma unroll
    for (int r = 0; r < 4; r++) seT[t * 4 + r] = emb[(v0 + r) * 256 + t];
    __syncthreads();

    const int l = t & 63, ds = t >> 6;
    const int cp0 = cq * 256 + l * 4;
    const int g = (cp0 >> 4) & 3;
    const int d0 = ((cp0 >> 6) << 4) + (cp0 & 15);
    const int c0 = g * 256 + d0;
    const float* wp = Wa + (size_t)(256 + ds * 64) * NC + c0;
    const float* up = Ua + (size_t)(256 + ds * 64) * NC + c0;
    const float* sT = seT + (ds * 64) * 4;

    f4 av[4] = {};
    for (int bb8 = 0; bb8 < 8; bb8++) {
      f4 wv8[8], uv8[8];
#pragma unroll
      for (int ii = 0; ii < 8; ii++) {  // 16 loads in flight
        const int dd = bb8 * 8 + ii;
        wv8[ii] = *(const f4*)(wp + (size_t)dd * NC);
        uv8[ii] = *(const f4*)(up + (size_t)dd * NC);
      }
      __builtin_amdgcn_sched_barrier(0);
#pragma unroll
      for (int ii = 0; ii < 8; ii++) {
        const int dd = bb8 * 8 + ii;
        const f4 wv = wv8[ii] + uv8[ii];
        const f4 s0 = *(const f4*)&sT[dd * 4];  // wave-uniform: broadcast
        av[0] += s0[0] * wv;
        av[1] += s0[1] * wv;
        av[2] += s0[2] * wv;
        av[3] += s0[3] * wv;
      }
    }
#pragma unroll
    for (int r = 0; r < 4; r++) *(f4*)&sa[((ds * 4 + r) * 64 + l) * 4] = av[r];
    __syncthreads();
    {
      const int r = t >> 6, fl = t & 63;   // 256 items: (r, l)
      f4 s = {0.f, 0.f, 0.f, 0.f};
#pragma unroll
      for (int d = 0; d < 4; d++) s += *(const f4*)&sa[((d * 4 + r) * 64 + fl) * 4];
      const int vvg = vgrp * 4 + r;
      const int kt = 16 + (vvg >> 5);
      const int lhi = (vvg >> 3) & 3;
      const int j = vvg & 7;
      const int cpb = cq * 256 + fl * 4;
#pragma unroll
      for (int i = 0; i < 4; i++) {
        const int cp = cpb + i;
        W0f[kt * 32768 + (cp >> 4) * 512 + (lhi * 16 + (cp & 15)) * 8 + j] = (_Float16)s[i];
      }
    }
  } else if (b < 2208) {
    // ---- role fold: coalesced f4 loads (batched), permuted scatter stores
    const int p = b - 2176;         // 0..15 -> W0f kt=p ; 16..31 -> Wlf kt=p-16
    const int kk = t >> 3;          // k within plane, 0..31
    const int tc = t & 7;           // column subgroup
    const int k = (p & 15) * 32 + kk;
    const float* rowp;
    const float* rowp2 = nullptr;
    if (p < 16) {
      rowp  = (k < 256) ? Wi + (size_t)k * NC : Wo + (size_t)(k - 256) * NC;
      rowp2 = (k < 256) ? Ui + (size_t)k * NC : Uo + (size_t)(k - 256) * NC;
    } else {
      rowp  = (k < 256) ? Ui + (size_t)k * NC : Uo + (size_t)(k - 256) * NC;
    }
    _Float16* dst = (p < 16) ? (W0f + p * 32768) : (Wlf + (p - 16) * 32768);
    const int lane0 = (kk >> 3) * 16;
    const int j = kk & 7;
    for (int bb8 = 0; bb8 < 4; bb8++) {
      f4 w8[8], u8[8];
#pragma unroll
      for (int ii = 0; ii < 8; ii++) {  // 8-16 loads in flight
        const int c = (bb8 * 8 + ii) * 32 + tc * 4;
        w8[ii] = *(const f4*)(rowp + c);
        if (p < 16) u8[ii] = *(const f4*)(rowp2 + c);
      }
      __builtin_amdgcn_sched_barrier(0);
#pragma unroll
      for (int ii = 0; ii < 8; ii++) {
        const int c = (bb8 * 8 + ii) * 32 + tc * 4;
        const int g = c >> 8, d = c & 255;
        const int nt = 4 * (d >> 4) + g;
        const int lb = lane0 + (d & 15);
        f4 v = w8[ii];
        if (p < 16) v += u8[ii];
#pragma unroll
        for (int q = 0; q < 4; q++)
          dst[nt * 512 + (lb + q) * 8 + j] = (_Float16)v[q];
      }
    }
  } else {
    // ---- role bias ----
#pragma unroll
    for (int i = 0; i < 4; i++) {
      const int cq = t * 4 + i;
      const int dd = cq >> 2, g = cq & 3;
      const int c = g * 256 + dd;
      biasq[cq] = bi[c] + bo[c] + bui[c] + buo[c];
    }
  }
}

// ---------------------------------------------------------------------------
// Iter-1 aggregate: gather fp16 h1 and form DELTA features in place:
//   X[row][0:512) = Nh(h1) - X_old[row][0:512)   (X_old = fp16 Nh(h0), exact
//   cancellation of the h0 part of z1). One row/wave, XCD-contiguous.
// ---------------------------------------------------------------------------
__global__ __launch_bounds__(256, 4) void agg_kernel(
    const _Float16* __restrict__ src,
    const int* __restrict__ iidx, const float* __restrict__ im,
    const int* __restrict__ oidx, const float* __restrict__ om,
    _Float16* __restrict__ X) {
  const int lane = threadIdx.x & 63;
  const int wid = threadIdx.x >> 6;
  const int b = blockIdx.x;
  const int row = (b & 7) * 1024 + (b >> 3) * 4 + wid;  // XCD-contiguous
  const int half = lane >> 5;
  const int lc = lane & 31;
  const int sel = lane >> 4, p16 = lane & 15;

  const int bb = row * Kn + p16;
  const int* ap = (sel == 0)   ? (iidx + bb)
                  : (sel == 1) ? ((const int*)im + bb)
                  : (sel == 2) ? (oidx + bb)
                               : ((const int*)om + bb);
  const int cmb = *ap;

  const int hb = row & ~511;
  const _Float16* hp = src + ((size_t)hb << 8) + (lc << 3);
  _Float16* xp = &X[(size_t)row * XS + half * 256 + lc * 8];

  const h8 xold = *(const h8*)xp;  // fp16 Nh(h0), read before overwrite

  h8 w[16];
#pragma unroll
  for (int k = 0; k < 16; k++) {  // 16 x 16B loads in flight
    const int ik = __shfl(cmb, (lane & 32) | k, 64);
    w[k] = *(const h8*)(hp + ((size_t)ik << 8));
  }
  __builtin_amdgcn_sched_barrier(0);  // keep gather issue above consume

  float acc[8] = {};
#pragma unroll
  for (int k = 0; k < 16; k++) {
    const float mk = __int_as_float(__shfl(cmb, (lane & 32) | 16 | k, 64));
#pragma unroll
    for (int c = 0; c < 8; c++) acc[c] += mk * (float)w[k][c];
  }

  h8 o;
#pragma unroll
  for (int c = 0; c < 8; c++) o[c] = (_Float16)(acc[c] - (float)xold[c]);
  *(h8*)xp = o;
}

// ---------------------------------------------------------------------------
// Fused MFMA GEMM + LSTM, 8-wave (R17 structure; A stride XS=640).
//   WITH_Z (iter 0): B = W0' (K=640); z0 = acc + bias; zq = fp16(z0);
//     LSTM0 (c=0) -> reps0 (NT store); h16 = fp16(h1). NO cbuf write —
//     c1 is recomputed in iter 1 from zq.
//   !WITH_Z (iter 1): B = Wl (K=512), A = Delta; z1 = zq + acc;
//     cold = sigm(z0_i)*tanh(z0_c)*mask (from zq, in-register);
//     LSTM1 -> reps1, hbuf, cbuf (NT stores).
// ---------------------------------------------------------------------------
template <bool WITH_Z>
__global__ __launch_bounds__(512) void fused_gemm(
    const _Float16* __restrict__ A, const _Float16* __restrict__ Wf,
    const float* __restrict__ biasq, _Float16* __restrict__ zq,
    const float* __restrict__ mask,
    float* __restrict__ reps, float* __restrict__ hbuf,
    _Float16* __restrict__ h16, float* __restrict__ cbuf) {
  constexpr int KT = WITH_Z ? 20 : 16;
  constexpr int D = 2;  // gloads per stage per THREAD (A + B)
  __shared__ __align__(16) _Float16 lds[3][8192];  // 48 KB

  const int wg = (blockIdx.x & 7) * 64 + (blockIdx.x >> 3);  // XCD swizzle
  const int bm = wg >> 3, bn = wg & 7;
  const int tid = threadIdx.x, lane = tid & 63, wid = tid >> 6;  // wid 0..7
  const int wr = wid >> 1, wc = wid & 1;   // 4x2 wave grid
  const int lr = lane & 15, lg = lane >> 4;

  f4 acc[2][4] = {};

  const _Float16* srcA0 = A + (size_t)(bm * 128 + wid * 16 + lr) * XS + lg * 8;
  const _Float16* srcB0 = Wf + ((size_t)bn * 8 + wid) * 512 + lane * 8;
  const int woff = wid * 512;

  auto stage = [&](int buf, int kt) {
    _Float16* base = lds[buf];
    gload16(base + woff, srcA0 + kt * 32);
    gload16(base + 4096 + woff, srcB0 + (size_t)kt * 32768);
  };

  stage(0, 0);
  stage(1, 1);
  asm volatile("s_waitcnt vmcnt(%0)" :: "i"(D) : "memory");
  __builtin_amdgcn_s_barrier();

  int cur = 0;
  for (int kt = 0; kt < KT; kt++) {
    if (kt + 2 < KT) stage(cur == 0 ? 2 : cur - 1, kt + 2);

    const _Float16* base = lds[cur];
    h8 a[2], bfr[4];
#pragma unroll
    for (int m = 0; m < 2; m++) a[m] = *(const h8*)&base[(wr * 2 + m) * 512 + lane * 8];
#pragma unroll
    for (int n = 0; n < 4; n++) bfr[n] = *(const h8*)&base[4096 + (wc * 4 + n) * 512 + lane * 8];
    asm volatile("s_waitcnt lgkmcnt(0)" ::: "memory");
    __builtin_amdgcn_sched_barrier(0);

    __builtin_amdgcn_s_setprio(1);
#pragma unroll
    for (int m = 0; m < 2; m++)
#pragma unroll
      for (int n = 0; n < 4; n++)
        acc[m][n] = __builtin_amdgcn_mfma_f32_16x16x32_f16(a[m], bfr[n], acc[m][n], 0, 0, 0);
    __builtin_amdgcn_s_setprio(0);

    if (kt + 2 < KT) asm volatile("s_waitcnt vmcnt(%0)" :: "i"(D) : "memory");
    else             asm volatile("s_waitcnt vmcnt(0)" ::: "memory");
    __builtin_amdgcn_sched_barrier(0);
    __builtin_amdgcn_s_barrier();

    cur = (cur == 2) ? 0 : cur + 1;
  }

  // epilogue: n-fragment index == gate g; lane lr picks output dim
  const int d = (bn * 2 + wc) * 16 + lr;
  const int row0 = bm * 128 + wr * 32;
  f4 bq = {0.f, 0.f, 0.f, 0.f};
  if (WITH_Z) bq = *(const f4*)&biasq[d * 4];
#pragma unroll
  for (int i = 0; i < 2; i++) {
#pragma unroll
    for (int r = 0; r < 4; r++) {
      const int row = row0 + i * 16 + lg * 4 + r;
      const size_t off = (size_t)row * Dd + d;
      const float mk = mask[row];
      float zi, zf, zo, zc, cold;
      if (WITH_Z) {
        zi = acc[i][0][r] + bq.x;
        zf = acc[i][1][r] + bq.y;
        zo = acc[i][2][r] + bq.z;
        zc = acc[i][3][r] + bq.w;
        h4 oz;
        oz[0] = (_Float16)zi; oz[1] = (_Float16)zf;
        oz[2] = (_Float16)zo; oz[3] = (_Float16)zc;
        *(h4*)&zq[off * 4] = oz;
        cold = 0.f;
      } else {
        const h4 zb = *(const h4*)&zq[off * 4];
        zi = (float)zb[0] + acc[i][0][r];
        zf = (float)zb[1] + acc[i][1][r];
        zo = (float)zb[2] + acc[i][2][r];
        zc = (float)zb[3] + acc[i][3][r];
        // recompute c1 from z0 (in zq) instead of cbuf roundtrip:
        cold = fsigm((float)zb[0]) * ftanh((float)zb[3]) * mk;
      }
      const float ig = fsigm(zi), fg = fsigm(zf), og = fsigm(zo), ci = ftanh(zc);
      const float cn = fg * cold + ig * ci;
      const float hn = og * ftanh(cn);
      const float hm = hn * mk;
      if (WITH_Z) {
        __builtin_nontemporal_store(hm, &reps[off]);  // reps0 (write-once)
        h16[off] = (_Float16)hm;                      // h1 for agg1 gathers
      } else {
        __builtin_nontemporal_store(hm, &reps[off]);       // reps1
        __builtin_nontemporal_store(hm, &hbuf[off]);       // final h
        __builtin_nontemporal_store(cn * mk, &cbuf[off]);  // final c
      }
    }
  }
}

// ---------------------------------------------------------------------------
extern "C" void kernel_launch(void* const* d_in, const int* in_sizes, int n_in,
                              void* d_out, int out_size, void* d_ws, size_t ws_size,
                              hipStream_t stream) {
  const float* node_reps = (const float*)d_in[0];
  const float* mask      = (const float*)d_in[1];
  const int*   in_idx    = (const int*)d_in[2];
  const int*   in_edges  = (const int*)d_in[3];
  const float* in_mask   = (const float*)d_in[4];
  const int*   out_idx   = (const int*)d_in[5];
  const int*   out_edges = (const int*)d_in[6];
  const float* out_mask  = (const float*)d_in[7];
  const float* edge_emb  = (const float*)d_in[8];
  const float* Wi  = (const float*)d_in[9];
  const float* Wo  = (const float*)d_in[10];
  const float* Ui  = (const float*)d_in[11];
  const float* Uo  = (const float*)d_in[12];
  const float* bi  = (const float*)d_in[13];
  const float* bo  = (const float*)d_in[14];
  const float* bui = (const float*)d_in[15];
  const float* buo = (const float*)d_in[16];

  float* out = (float*)d_out;
  const size_t MD = (size_t)MR * Dd;
  float* reps0 = out;
  float* reps1 = out + MD;
  float* hbuf  = out + 2 * MD;
  float* cbuf  = out + 3 * MD;

  _Float16* X    = (_Float16*)d_ws;                 // 8192*640 fp16 (10.5 MB)
  _Float16* zq   = X + (size_t)MR * XS;             // 16 MB
  _Float16* W0f  = zq + (size_t)MR * NC;            // 640*1024 (1.25 MB)
  _Float16* Wlf  = W0f + 640 * 1024;                // 512*1024 (1 MB)
  _Float16* h16  = Wlf + 512 * 1024;                // 4 MB (fp16 h1)
  float*    biasq = (float*)(h16 + (size_t)MR * Dd);

  // 1. agg0(f32 gathers + bins) || P-GEMM || fold || bias
  mega2_kernel<<<2209, 256, 0, stream>>>(node_reps, edge_emb, in_idx, in_mask,
                                         out_idx, out_mask, in_edges, out_edges,
                                         Wi, Wo, Ui, Uo, bi, bo, bui, buo,
                                         X, W0f, Wlf, biasq);
  // 2. gemm0 (8-wave): z0 = X(K=640) @ W0' + bias; zq; LSTM0 -> reps0, h16
  fused_gemm<true><<<512, 512, 0, stream>>>(
      X, W0f, biasq, zq, mask, reps0, nullptr, h16, nullptr);
  // 3. agg1: X[:, :512) = Nh(h1) - X_old  (delta features, in place)
  agg_kernel<<<2048, 256, 0, stream>>>(h16, in_idx, in_mask, out_idx, out_mask, X);
  // 4. gemm1 (8-wave): z1 = zq + Delta(K=512) @ Wl; c_old from zq;
  //    LSTM1 -> reps1, hbuf, cbuf
  fused_gemm<false><<<512, 512, 0, stream>>>(
      X, Wlf, nullptr, zq, mask, reps1, hbuf, nullptr, cbuf);
}